// Round 7
// baseline (218.209 us; speedup 1.0000x reference)
//
#include <hip/hip_runtime.h>

// Problem constants (reference: T=4096, N_ENVS=2048, fp32)
#define TT    4096
#define NENV  2048
#define L     8                   // timesteps per chunk
#define NCH   (TT / L)            // 512 chunks
#define CTIL  256                 // scalar columns per tile-block
#define NCB   (NENV / CTIL)       // 8 col-blocks per chunk
#define NBLKL (NCH * NCB)         // 4096 blocks for k1L/k3L

#define GAMMA 0.99f
#define GL    (0.99f * 0.95f)

typedef unsigned short u16;
typedef unsigned char  u8;
typedef unsigned int   u32;
typedef float v4f __attribute__((ext_vector_type(4)));
typedef float v2f __attribute__((ext_vector_type(2)));

// float -> bf16 (round-to-nearest-even), low 16 bits
static __device__ __forceinline__ u32 bf16_rne(float f) {
    const u32 u = __float_as_uint(f);
    return (u + 0x7FFFu + ((u >> 16) & 1u)) >> 16;
}

// Stage 1KB (wave x 16B) global -> LDS. Async DMA: no result VGPRs, so
// in-flight depth is bounded by vmcnt (63), not the register file. LDS
// dest is wave-uniform base + lane*16 (HW rule); global src is per-lane.
static __device__ __forceinline__ void stage16(const void* g, void* l, int lane) {
#if defined(__has_builtin) && __has_builtin(__builtin_amdgcn_global_load_lds)
    __builtin_amdgcn_global_load_lds(
        (const __attribute__((address_space(1))) void*)((const char*)g + 16 * lane),
        (__attribute__((address_space(3))) void*)l, 16, 0, 0);
#else
    ((v4f*)l)[lane] = ((const v4f*)g)[lane];
#endif
}

// ---- k1L: LDS-staged per-chunk affine (A,B) + bf16 di + done-mask ----
__global__ __launch_bounds__(256, 4) void gae_k1L(
    const float* __restrict__ rp,  const float* __restrict__ vp,
    const float* __restrict__ np,  const int*   __restrict__ dp,
    float* __restrict__ wsA, float* __restrict__ wsB,
    u16* __restrict__ dib, u8* __restrict__ msk)
{
    __shared__ float smR[L][CTIL], smV[L][CTIL], smNV[L][CTIL];   // 3 x 8KB
    __shared__ int   smDN[L][CTIL];                               // 8KB

    const int bid   = (int)blockIdx.x;
    const int chunk = bid >> 3;
    const int cb    = bid & 7;
    const int t0    = chunk * L;
    const int tid   = (int)threadIdx.x;
    const int w     = tid >> 6;
    const int lane  = tid & 63;

    // wave w stages rows {2w, 2w+1} of all 4 arrays: 8 x 1KB per wave
#pragma unroll
    for (int k = 0; k < 2; ++k) {
        const int row = 2 * w + k;
        const size_t go = (size_t)(t0 + row) * NENV + cb * CTIL;
        stage16(rp + go, &smR[row][0],  lane);
        stage16(vp + go, &smV[row][0],  lane);
        stage16(np + go, &smNV[row][0], lane);
        stage16(dp + go, &smDN[row][0], lane);
    }
    asm volatile("s_waitcnt vmcnt(0)" ::: "memory");
    __syncthreads();

    const int c    = tid;                 // col within tile
    const int gcol = cb * CTIL + c;

    float A = 1.0f, B = 0.0f;
    u32 m = 0u;
    u32 db0, db1, db2, db3, db4, db5, db6, db7;
#define K1L_STEP(i, dbv)                                         \
    {                                                            \
        const float r  = smR[i][c];                              \
        const float v  = smV[i][c];                              \
        const float nv = smNV[i][c];                             \
        const int   dn = smDN[i][c];                             \
        const float nd = dn ? 0.0f : 1.0f;                       \
        const float di = r + GAMMA * nv * nd - v;                \
        const float cc = GL * nd;                                \
        B = di + cc * B;                                         \
        A = cc * A;                                              \
        dbv = bf16_rne(di);                                      \
        m |= (dn ? 1u : 0u) << (i);                              \
    }
    K1L_STEP(7, db7) K1L_STEP(6, db6) K1L_STEP(5, db5) K1L_STEP(4, db4)
    K1L_STEP(3, db3) K1L_STEP(2, db2) K1L_STEP(1, db1) K1L_STEP(0, db0)
#undef K1L_STEP

    const size_t col = (size_t)chunk * NENV + gcol;
    wsA[col] = A;
    wsB[col] = B;
    msk[col] = (u8)m;
    // di layout [NCH][NENV][8] bf16 -> one aligned 16B store per thread
    const uint4 pk = make_uint4(db0 | (db1 << 16), db2 | (db3 << 16),
                                db4 | (db5 << 16), db6 | (db7 << 16));
    *(uint4*)&dib[col * L] = pk;
}

// ---- k2: full-depth serial scan over 512 chunk affines (proven) ----
__global__ __launch_bounds__(64) void gae_k2(
    const float* __restrict__ As, float* __restrict__ Bs)
{
    const int col = (int)blockIdx.x * 64 + (int)threadIdx.x;   // 32 blocks
    float a0[16], b0[16], a1[16], b1[16];
    float g = 0.0f;
#define P2_PREFETCH(abuf, bbuf, grp_)                        \
    _Pragma("unroll")                                        \
    for (int j = 0; j < 16; ++j) {                           \
        const int cc = NCH - 1 - (grp_) * 16 - j;            \
        abuf[j] = As[cc * NENV + col];                       \
        bbuf[j] = Bs[cc * NENV + col];                       \
    }
#define P2_PROCESS(abuf, bbuf, grp_)                         \
    _Pragma("unroll")                                        \
    for (int j = 0; j < 16; ++j) {                           \
        const int cc = NCH - 1 - (grp_) * 16 - j;            \
        Bs[cc * NENV + col] = g;                             \
        g = fmaf(abuf[j], g, bbuf[j]);                       \
    }
    P2_PREFETCH(a0, b0, 0)
    for (int grp = 0; grp < NCH / 16; grp += 2) {
        P2_PREFETCH(a1, b1, grp + 1)
        P2_PROCESS(a0, b0, grp)
        if (grp + 2 < NCH / 16) { P2_PREFETCH(a0, b0, grp + 2) }
        P2_PROCESS(a1, b1, grp + 1)
    }
#undef P2_PREFETCH
#undef P2_PROCESS
}

// ---- k3L: LDS-staged replay; float4 nt output flush via LDS repack ----
__global__ __launch_bounds__(256, 4) void gae_k3L(
    const float* __restrict__ vp,
    const u16* __restrict__ dib, const u8* __restrict__ msk,
    const float* __restrict__ gin,
    float* __restrict__ adv, float* __restrict__ ret)
{
    __shared__ float smV[L][CTIL];     // 8KB
    __shared__ u16   smD[CTIL][L];     // 4KB ([col][t] -> contiguous stage)
    __shared__ float scr[L][CTIL];     // 8KB output repack

    const int bid   = (int)blockIdx.x;
    const int chunk = bid >> 3;
    const int cb    = bid & 7;
    const int t0    = chunk * L;
    const int tid   = (int)threadIdx.x;
    const int w     = tid >> 6;
    const int lane  = tid & 63;

    // stage v rows (2 x 1KB per wave) + dib tile slice (1 x 1KB per wave)
#pragma unroll
    for (int k = 0; k < 2; ++k) {
        const int row = 2 * w + k;
        stage16(vp + (size_t)(t0 + row) * NENV + cb * CTIL, &smV[row][0], lane);
    }
    stage16(dib + ((size_t)chunk * NENV + cb * CTIL) * L + (size_t)w * 512,
            &smD[w * 64][0], lane);

    const int c    = tid;
    const int gcol = cb * CTIL + c;
    const size_t col = (size_t)chunk * NENV + gcol;
    const u32  m = msk[col];     // scalar loads hidden under the stage wait
    float g      = gin[col];

    asm volatile("s_waitcnt vmcnt(0)" ::: "memory");
    __syncthreads();

    const u32* dc = (const u32*)&smD[c][0];
    const u32 u0 = dc[0], u1 = dc[1], u2 = dc[2], u3 = dc[3];
    float ar[L], rr[L];
#define K3L_STEP(i, uu, hi)                                               \
    {                                                                     \
        const float di = __uint_as_float((hi) ? ((uu) & 0xFFFF0000u)      \
                                              : ((uu) << 16));            \
        const float cc = ((m >> (i)) & 1u) ? 0.0f : GL;                   \
        g = di + cc * g;                                                  \
        ar[i] = g;                                                        \
        rr[i] = g + smV[i][c];                                            \
    }
    K3L_STEP(7, u3, 1) K3L_STEP(6, u3, 0) K3L_STEP(5, u2, 1) K3L_STEP(4, u2, 0)
    K3L_STEP(3, u1, 1) K3L_STEP(2, u1, 0) K3L_STEP(1, u0, 1) K3L_STEP(0, u0, 0)
#undef K3L_STEP

    // repack + wide nt flush: thread j flushes row j>>5, floats (j&31)*8..+8
    const int fr = tid >> 5, fs = tid & 31;
#pragma unroll
    for (int i = 0; i < L; ++i) scr[i][c] = ar[i];
    __syncthreads();
    {
        const float* s = &scr[fr][fs * 8];
        const v4f q0 = *(const v4f*)s, q1 = *(const v4f*)(s + 4);
        float* o = adv + (size_t)(t0 + fr) * NENV + cb * CTIL + fs * 8;
        __builtin_nontemporal_store(q0, (v4f*)o);
        __builtin_nontemporal_store(q1, (v4f*)(o + 4));
    }
    __syncthreads();
#pragma unroll
    for (int i = 0; i < L; ++i) scr[i][c] = rr[i];
    __syncthreads();
    {
        const float* s = &scr[fr][fs * 8];
        const v4f q0 = *(const v4f*)s, q1 = *(const v4f*)(s + 4);
        float* o = ret + (size_t)(t0 + fr) * NENV + cb * CTIL + fs * 8;
        __builtin_nontemporal_store(q0, (v4f*)o);
        __builtin_nontemporal_store(q1, (v4f*)(o + 4));
    }
}

// ============ fallback path (R4 float2 trio, proven) ============
#define N2    (NENV / 2)
#define NBLKF (NCH * 4)
__global__ __launch_bounds__(256, 8) void gae_k1(
    const float2* __restrict__ rp,  const float2* __restrict__ vp,
    const float2* __restrict__ np,  const int2*   __restrict__ dp,
    float2* __restrict__ wsA, float2* __restrict__ wsB)
{
    const int chunk = (int)blockIdx.x >> 2;
    const int c2    = (((int)blockIdx.x & 3) << 8) | (int)threadIdx.x;
    const int base  = chunk * (L * N2) + c2;
    float Ax = 1.f, Ay = 1.f, Bx = 0.f, By = 0.f;
#pragma unroll
    for (int i = L - 1; i >= 0; --i) {
        const int idx   = base + i * N2;
        const float2 r  = rp[idx];
        const float2 v  = vp[idx];
        const float2 nv = np[idx];
        const int2   dn = dp[idx];
        const float ndx = dn.x ? 0.f : 1.f;
        const float dix = r.x + GAMMA * nv.x * ndx - v.x;
        Bx = dix + GL * ndx * Bx;  Ax = GL * ndx * Ax;
        const float ndy = dn.y ? 0.f : 1.f;
        const float diy = r.y + GAMMA * nv.y * ndy - v.y;
        By = diy + GL * ndy * By;  Ay = GL * ndy * Ay;
    }
    wsA[chunk * N2 + c2] = make_float2(Ax, Ay);
    wsB[chunk * N2 + c2] = make_float2(Bx, By);
}

__global__ __launch_bounds__(256, 8) void gae_k3(
    const float2* __restrict__ rp,  const float2* __restrict__ vp,
    const float2* __restrict__ np,  const int2*   __restrict__ dp,
    const float2* __restrict__ gin,
    float2* __restrict__ adv2, float2* __restrict__ ret2)
{
    const int chunk = (int)blockIdx.x >> 2;
    const int c2    = (((int)blockIdx.x & 3) << 8) | (int)threadIdx.x;
    const int base  = chunk * (L * N2) + c2;
    const float2 g0 = gin[chunk * N2 + c2];
    float gx = g0.x, gy = g0.y;
#pragma unroll
    for (int i = L - 1; i >= 0; --i) {
        const int idx   = base + i * N2;
        const float2 r  = rp[idx];
        const float2 v  = vp[idx];
        const float2 nv = np[idx];
        const int2   dn = dp[idx];
        const float ndx = dn.x ? 0.f : 1.f;
        gx = (r.x + GAMMA * nv.x * ndx - v.x) + GL * ndx * gx;
        const float ndy = dn.y ? 0.f : 1.f;
        gy = (r.y + GAMMA * nv.y * ndy - v.y) + GL * ndy * gy;
        v2f av; av.x = gx;       av.y = gy;
        v2f tv; tv.x = gx + v.x; tv.y = gy + v.y;
        __builtin_nontemporal_store(av, (v2f*)&adv2[idx]);
        __builtin_nontemporal_store(tv, (v2f*)&ret2[idx]);
    }
}

extern "C" void kernel_launch(void* const* d_in, const int* in_sizes, int n_in,
                              void* d_out, int out_size, void* d_ws, size_t ws_size,
                              hipStream_t stream) {
    const float* rp = (const float*)d_in[0];
    const float* vp = (const float*)d_in[1];
    const float* np = (const float*)d_in[2];
    const int*   dp = (const int*)d_in[3];

    float* adv = (float*)d_out;
    float* ret = adv + (size_t)TT * NENV;

    float* wsA = (float*)d_ws;                       // 4 MiB
    float* wsB = wsA + (size_t)NCH * NENV;           // 4 MiB -> g-in after k2
    u16*   dib = (u16*)((char*)d_ws + ((size_t)8 << 20));   // 16 MiB
    u8*    msk = (u8*)(dib + (size_t)TT * NENV);            //  1 MiB

    const size_t need = ((size_t)8 << 20) + (size_t)TT * NENV * 2
                      + (size_t)NCH * NENV;          // 25 MiB (same as R6, proven)

    if (ws_size >= need) {
        gae_k1L<<<NBLKL, 256, 0, stream>>>(rp, vp, np, dp, wsA, wsB, dib, msk);
        gae_k2 <<<NENV / 64, 64, 0, stream>>>(wsA, wsB);
        gae_k3L<<<NBLKL, 256, 0, stream>>>(vp, dib, msk, wsB, adv, ret);
    } else {
        gae_k1<<<NBLKF, 256, 0, stream>>>((const float2*)rp, (const float2*)vp,
                                          (const float2*)np, (const int2*)dp,
                                          (float2*)wsA, (float2*)wsB);
        gae_k2<<<NENV / 64, 64, 0, stream>>>(wsA, wsB);
        gae_k3<<<NBLKF, 256, 0, stream>>>((const float2*)rp, (const float2*)vp,
                                          (const float2*)np, (const int2*)dp,
                                          (const float2*)wsB,
                                          (float2*)adv, (float2*)ret);
    }
}